// Round 2
// baseline (1394.822 us; speedup 1.0000x reference)
//
#include <hip/hip_runtime.h>
#include <math.h>

#define ND_ROWS 16384
#define DDIM    256
#define KCODES  8192
#define NSPLIT  4
#define KSEG    (KCODES / NSPLIT)   // 2048
#define TM      128
#define TN      128
#define TK      32

// ---------------------------------------------------------------------------
// ws layout (float offsets):
//   ne        [0,      8192)
//   nx        [8192,   24576)
//   val_part  [24576,  90112)   4 x 16384 floats
//   idx_part  [90112,  155648)  4 x 16384 ints
//   counts    [155648, 163840)  8192 ints   (memset 0 each call)
//   sse       [163840, 163842)  2 floats    (memset 0 each call)
// total ~640 KB
// ---------------------------------------------------------------------------

__global__ __launch_bounds__(256) void norms_kernel(const float* __restrict__ x,
                                                    const float* __restrict__ emb,
                                                    float* __restrict__ ne,
                                                    float* __restrict__ nx) {
    int wave = (blockIdx.x << 2) + (threadIdx.x >> 6);   // 4 waves/block
    int lane = threadIdx.x & 63;
    const float* src;
    float* dst;
    if (wave < KCODES) { src = emb + (size_t)wave * DDIM; dst = ne + wave; }
    else               { int r = wave - KCODES; src = x + (size_t)r * DDIM; dst = nx + r; }
    float4 v = ((const float4*)src)[lane];               // 64 lanes x 4 = 256
    float s = v.x*v.x + v.y*v.y + v.z*v.z + v.w*v.w;
    #pragma unroll
    for (int m = 32; m; m >>= 1) s += __shfl_xor(s, m, 64);
    if (lane == 0) *dst = s;
}

// 128x128 tile argmin GEMM; each block handles TM rows x KSEG codes.
// micro-tile 8x8, strided: row = ty + 16*r, col = tx + 16*c  ->
// LDS fragment reads are b32 with <=2-way bank aliasing (free on CDNA4).
__global__ __launch_bounds__(256, 2) void argmin_kernel(
    const float* __restrict__ x, const float* __restrict__ emb,
    const float* __restrict__ nx, const float* __restrict__ ne,
    float* __restrict__ val_part, int* __restrict__ idx_part) {
    __shared__ float As[TM][TK + 4];   // natural [row][k], pad 36 floats
    __shared__ float Bs[TN][TK + 4];
    __shared__ float sval[TM][16];
    __shared__ int   sidx[TM][16];

    const int tid = threadIdx.x;
    const int tx  = tid & 15;
    const int ty  = tid >> 4;
    const int rt  = blockIdx.x >> 2;   // 128 row tiles
    const int ks  = blockIdx.x & 3;    // 4 code splits
    const int rowBase  = rt * TM;
    const int codeBase = ks * KSEG;

    float nxr[8];
    #pragma unroll
    for (int r = 0; r < 8; ++r) nxr[r] = nx[rowBase + ty + 16 * r];

    float minval[8];
    int   minidx[8];
    #pragma unroll
    for (int r = 0; r < 8; ++r) { minval[r] = 3.402823466e+38f; minidx[r] = 0; }

    for (int jt = 0; jt < KSEG; jt += TN) {
        float dot[8][8];
        #pragma unroll
        for (int r = 0; r < 8; ++r)
            #pragma unroll
            for (int c = 0; c < 8; ++c) dot[r][c] = 0.0f;

        for (int kc = 0; kc < DDIM; kc += TK) {
            __syncthreads();   // protect LDS from previous iteration's readers
            #pragma unroll
            for (int i = 0; i < 4; ++i) {
                int f   = tid + (i << 8);        // [0,1024)
                int row = f >> 3;                // 8 float4 per row-chunk
                int k4  = (f & 7) << 2;
                float4 va = *(const float4*)(x   + (size_t)(rowBase  + row) * DDIM + kc + k4);
                *(float4*)(&As[row][k4]) = va;
                float4 vb = *(const float4*)(emb + (size_t)(codeBase + jt + row) * DDIM + kc + k4);
                *(float4*)(&Bs[row][k4]) = vb;
            }
            __syncthreads();
            #pragma unroll 4
            for (int kk = 0; kk < TK; ++kk) {
                float a[8], b[8];
                #pragma unroll
                for (int r = 0; r < 8; ++r) a[r] = As[ty + 16 * r][kk];
                #pragma unroll
                for (int c = 0; c < 8; ++c) b[c] = Bs[tx + 16 * c][kk];
                #pragma unroll
                for (int r = 0; r < 8; ++r)
                    #pragma unroll
                    for (int c = 0; c < 8; ++c)
                        dot[r][c] = fmaf(a[r], b[c], dot[r][c]);
            }
        }
        // epilogue: distances + running argmin (cols ascending -> first-min-wins)
        #pragma unroll
        for (int c = 0; c < 8; ++c) {
            int col = codeBase + jt + tx + 16 * c;
            float nec = ne[col];
            #pragma unroll
            for (int r = 0; r < 8; ++r) {
                float dist = (nxr[r] + nec) - 2.0f * dot[r][c];
                if (dist < minval[r]) { minval[r] = dist; minidx[r] = col; }
            }
        }
    }

    #pragma unroll
    for (int r = 0; r < 8; ++r) {
        sval[ty + 16 * r][tx] = minval[r];
        sidx[ty + 16 * r][tx] = minidx[r];
    }
    __syncthreads();
    if (tid < TM) {
        float bv = sval[tid][0];
        int   bi = sidx[tid][0];
        #pragma unroll
        for (int t = 1; t < 16; ++t) {
            float v = sval[tid][t]; int i2 = sidx[tid][t];
            if (v < bv || (v == bv && i2 < bi)) { bv = v; bi = i2; }
        }
        val_part[ks * ND_ROWS + rowBase + tid] = bv;
        idx_part[ks * ND_ROWS + rowBase + tid] = bi;
    }
}

// merge splits, gather codebook row, write quantized_sg + float index,
// accumulate SSEs and histogram. One wave per row.
__global__ __launch_bounds__(256) void finalize_kernel(
    const float* __restrict__ x, const float* __restrict__ emb,
    const float* __restrict__ val_part, const int* __restrict__ idx_part,
    float* __restrict__ out_q, float* __restrict__ out_idx,
    int* __restrict__ counts, float* __restrict__ sse) {
    int row  = (blockIdx.x << 2) + (threadIdx.x >> 6);
    int lane = threadIdx.x & 63;

    float bv = val_part[row];
    int   bi = idx_part[row];
    #pragma unroll
    for (int p = 1; p < NSPLIT; ++p) {
        float v  = val_part[p * ND_ROWS + row];
        int   i2 = idx_part[p * ND_ROWS + row];
        if (v < bv || (v == bv && i2 < bi)) { bv = v; bi = i2; }
    }

    float4 xv = ((const float4*)(x   + (size_t)row * DDIM))[lane];
    float4 ev = ((const float4*)(emb + (size_t)bi  * DDIM))[lane];
    float4 q;
    q.x = xv.x + (ev.x - xv.x);
    q.y = xv.y + (ev.y - xv.y);
    q.z = xv.z + (ev.z - xv.z);
    q.w = xv.w + (ev.w - xv.w);
    ((float4*)(out_q + (size_t)row * DDIM))[lane] = q;

    float de = (ev.x - xv.x) * (ev.x - xv.x) + (ev.y - xv.y) * (ev.y - xv.y)
             + (ev.z - xv.z) * (ev.z - xv.z) + (ev.w - xv.w) * (ev.w - xv.w);
    float dq = (q.x - ev.x) * (q.x - ev.x) + (q.y - ev.y) * (q.y - ev.y)
             + (q.z - ev.z) * (q.z - ev.z) + (q.w - ev.w) * (q.w - ev.w);
    #pragma unroll
    for (int m = 32; m; m >>= 1) {
        de += __shfl_xor(de, m, 64);
        dq += __shfl_xor(dq, m, 64);
    }
    if (lane == 0) {
        out_idx[row] = (float)bi;
        atomicAdd(&counts[bi], 1);
        atomicAdd(&sse[0], de);   // e_latent numerator
        atomicAdd(&sse[1], dq);   // q_latent numerator
    }
}

__global__ __launch_bounds__(256) void scalars_kernel(
    const int* __restrict__ counts, const float* __restrict__ sse,
    float* __restrict__ out_loss, float* __restrict__ out_perp) {
    __shared__ float red[256];
    float local = 0.0f;
    for (int k = threadIdx.x; k < KCODES; k += 256) {
        float p = (float)counts[k] * (1.0f / (float)ND_ROWS);
        local += p * logf(p + 1e-10f);   // p==0 contributes exactly 0
    }
    red[threadIdx.x] = local;
    __syncthreads();
    for (int s = 128; s; s >>= 1) {
        if (threadIdx.x < s) red[threadIdx.x] += red[threadIdx.x + s];
        __syncthreads();
    }
    if (threadIdx.x == 0) {
        *out_perp = expf(-red[0]);
        float invn = 1.0f / (float)(ND_ROWS * DDIM);
        *out_loss = sse[1] * invn + 0.25f * (sse[0] * invn);
    }
}

extern "C" void kernel_launch(void* const* d_in, const int* in_sizes, int n_in,
                              void* d_out, int out_size, void* d_ws, size_t ws_size,
                              hipStream_t stream) {
    const float* x   = (const float*)d_in[0];
    const float* emb = (const float*)d_in[1];

    float* ws       = (float*)d_ws;
    float* ne       = ws;                    // 8192
    float* nx       = ws + 8192;             // 16384
    float* val_part = ws + 24576;            // 4*16384 floats
    int*   idx_part = (int*)(ws + 90112);    // 4*16384 ints
    int*   counts   = (int*)(ws + 155648);   // 8192 ints
    float* sse      = ws + 163840;           // 2 floats

    float* out_q    = (float*)d_out;                       // 16*1024*256
    float* out_idx  = out_q + (size_t)ND_ROWS * DDIM;      // 16384
    float* out_loss = out_idx + ND_ROWS;                   // 1
    float* out_perp = out_loss + 1;                        // 1

    // counts + sse are contiguous: one async memset (graph-capture safe)
    hipMemsetAsync(counts, 0, KCODES * sizeof(int) + 2 * sizeof(float), stream);

    // 24576 norm vectors, one wave each, 4 waves/block -> 6144 blocks
    // (R1 bug: divided by 64 twice -> only 384 waves launched, ne[384..] poison)
    norms_kernel<<<(KCODES + ND_ROWS) / 4, 256, 0, stream>>>(x, emb, ne, nx);
    argmin_kernel<<<(ND_ROWS / TM) * NSPLIT, 256, 0, stream>>>(x, emb, nx, ne,
                                                               val_part, idx_part);
    finalize_kernel<<<ND_ROWS / 4, 256, 0, stream>>>(x, emb, val_part, idx_part,
                                                     out_q, out_idx, counts, sse);
    scalars_kernel<<<1, 256, 0, stream>>>(counts, sse, out_loss, out_perp);
}

// Round 3
// 910.997 us; speedup vs baseline: 1.5311x; 1.5311x over previous
//
#include <hip/hip_runtime.h>
#include <math.h>
#include <stdint.h>

#define ND_ROWS 16384
#define DDIM    256
#define KCODES  8192
#define NSPLIT  4
#define KSEG    (KCODES / NSPLIT)   // 2048

typedef _Float16 f16x4 __attribute__((ext_vector_type(4)));
typedef _Float16 f16x8 __attribute__((ext_vector_type(8)));
typedef float    f32x4 __attribute__((ext_vector_type(4)));

// ---------------------------------------------------------------------------
// ws layout (float offsets):
//   ne        [0,      8192)
//   nx        [8192,   24576)
//   val_part  [24576,  90112)    4 x 16384 floats
//   idx_part  [90112,  155648)   4 x 16384 ints
//   counts    [155648, 163840)   8192 ints   (memset 0 each call)
//   sse       [163840, 163842)   2 floats    (memset 0 each call)
//   Ap        [163848, ...)      16384x512 f16  ([x_hi | x_lo])   16.8 MB
//   Bp        Ap + 8388608       8192x512  f16  ([e_hi | e_lo])    8.4 MB
// total ~25.9 MB
// ---------------------------------------------------------------------------

__device__ __attribute__((always_inline)) inline void load_lds16(const void* g, void* l) {
    __builtin_amdgcn_global_load_lds((const __attribute__((address_space(1))) void*)g,
                                     (__attribute__((address_space(3))) void*)l, 16, 0, 0);
}

__global__ __launch_bounds__(256) void norms_kernel(const float* __restrict__ x,
                                                    const float* __restrict__ emb,
                                                    float* __restrict__ ne,
                                                    float* __restrict__ nx) {
    int wave = (blockIdx.x << 2) + (threadIdx.x >> 6);   // 4 waves/block
    int lane = threadIdx.x & 63;
    const float* src;
    float* dst;
    if (wave < KCODES) { src = emb + (size_t)wave * DDIM; dst = ne + wave; }
    else               { int r = wave - KCODES; src = x + (size_t)r * DDIM; dst = nx + r; }
    float4 v = ((const float4*)src)[lane];
    float s = v.x*v.x + v.y*v.y + v.z*v.z + v.w*v.w;
    #pragma unroll
    for (int m = 32; m; m >>= 1) s += __shfl_xor(s, m, 64);
    if (lane == 0) *dst = s;
}

// fp32 -> fp16 hi/lo split, packed [hi(256) | lo(256)] per row.
__global__ __launch_bounds__(256) void prep_kernel(const float* __restrict__ x,
                                                   const float* __restrict__ emb,
                                                   _Float16* __restrict__ Ap,
                                                   _Float16* __restrict__ Bp) {
    int t   = blockIdx.x * 256 + threadIdx.x;   // [0, 24576*64)
    int row = t >> 6;
    int k4  = (t & 63) << 2;
    const float* src;
    _Float16* dst;
    if (row < ND_ROWS) { src = x   + (size_t)row * DDIM;             dst = Ap + (size_t)row * 512; }
    else               { src = emb + (size_t)(row - ND_ROWS) * DDIM; dst = Bp + (size_t)(row - ND_ROWS) * 512; }
    float4 v = *(const float4*)(src + k4);
    f16x4 hi, lo;
    hi[0] = (_Float16)v.x; lo[0] = (_Float16)(v.x - (float)hi[0]);
    hi[1] = (_Float16)v.y; lo[1] = (_Float16)(v.y - (float)hi[1]);
    hi[2] = (_Float16)v.z; lo[2] = (_Float16)(v.z - (float)hi[2]);
    hi[3] = (_Float16)v.w; lo[3] = (_Float16)(v.w - (float)hi[3]);
    *(f16x4*)(dst + k4)       = hi;
    *(f16x4*)(dst + 256 + k4) = lo;
}

// MFMA argmin GEMM: logical K'=768 = [x1.e1 | x1.e2 | x2.e1].
// Block = 128 rows x 2048 codes (4-way col split), 4 waves of 64x64.
__global__ __launch_bounds__(256, 2) void argmin_mfma(
    const _Float16* __restrict__ Ap, const _Float16* __restrict__ Bp,
    const float* __restrict__ nx, const float* __restrict__ ne,
    float* __restrict__ val_part, int* __restrict__ idx_part) {
    __shared__ __align__(16) _Float16 As[128 * 32];   // [row][32 halves], 64B/row, 8KB
    __shared__ __align__(16) _Float16 Bs[128 * 32];
    __shared__ float sval2[2][128];
    __shared__ int   sidx2[2][128];

    const int tid  = threadIdx.x;
    const int lane = tid & 63;
    const int w    = tid >> 6;
    const int wx   = w & 1;
    const int wy   = w >> 1;
    const int quad = lane >> 4;
    const int t16  = lane & 15;

    const int rt       = blockIdx.x >> 2;
    const int ks       = blockIdx.x & 3;
    const int rowBase  = rt * 128;
    const int codeBase = ks * KSEG;

    // staging geometry: wave w stages rows [w*32, w*32+32) of each tile,
    // lane covers (row = w*32 + j*16 + lane/4, bytes (lane%4)*16 of the 64B chunk)
    const int srow  = (w << 5) + (lane >> 2);
    const int sbyte = (lane & 3) << 4;

    float nxr[16];
    #pragma unroll
    for (int mt = 0; mt < 4; ++mt)
        #pragma unroll
        for (int r = 0; r < 4; ++r)
            nxr[mt * 4 + r] = nx[rowBase + wy * 64 + mt * 16 + quad * 4 + r];

    float minval[16];
    int   minidx[16];
    #pragma unroll
    for (int i = 0; i < 16; ++i) { minval[i] = 3.402823466e+38f; minidx[i] = 0; }

    for (int jt = 0; jt < 16; ++jt) {
        const int colBase = codeBase + jt * 128;
        f32x4 acc[4][4];
        #pragma unroll
        for (int mt = 0; mt < 4; ++mt)
            #pragma unroll
            for (int nt = 0; nt < 4; ++nt) {
                f32x4 z = {0.0f, 0.0f, 0.0f, 0.0f};
                acc[mt][nt] = z;
            }

        for (int kc = 0; kc < 768; kc += 32) {
            const int a_k = (kc < 256) ? kc : kc - 256;   // [x1 | x1 | x2] source map
            const int b_k = (kc < 512) ? kc : kc - 512;   // [e1 | e2 | e1] source map
            __syncthreads();   // previous iter's ds_reads done before overwrite
            #pragma unroll
            for (int j = 0; j < 2; ++j) {
                const char* gA = (const char*)(Ap + (size_t)(rowBase + srow + j * 16) * 512 + a_k) + sbyte;
                load_lds16(gA, (char*)As + (w << 11) + (j << 10));
                const char* gB = (const char*)(Bp + (size_t)(colBase + srow + j * 16) * 512 + b_k) + sbyte;
                load_lds16(gB, (char*)Bs + (w << 11) + (j << 10));
            }
            __syncthreads();   // drains vmcnt: staged data visible

            f16x8 af[4], bf[4];
            #pragma unroll
            for (int mt = 0; mt < 4; ++mt)
                af[mt] = *(const f16x8*)((const char*)As + (wy * 64 + mt * 16 + t16) * 64 + quad * 16);
            #pragma unroll
            for (int nt = 0; nt < 4; ++nt)
                bf[nt] = *(const f16x8*)((const char*)Bs + (wx * 64 + nt * 16 + t16) * 64 + quad * 16);
            #pragma unroll
            for (int mt = 0; mt < 4; ++mt)
                #pragma unroll
                for (int nt = 0; nt < 4; ++nt)
                    acc[mt][nt] = __builtin_amdgcn_mfma_f32_16x16x32_f16(af[mt], bf[nt], acc[mt][nt], 0, 0, 0);
        }

        // epilogue: dist = nx + ne - 2*dot; running argmin (cols ascending per lane)
        #pragma unroll
        for (int nt = 0; nt < 4; ++nt) {
            int col = colBase + wx * 64 + nt * 16 + t16;
            float nec = ne[col];
            #pragma unroll
            for (int mt = 0; mt < 4; ++mt)
                #pragma unroll
                for (int r = 0; r < 4; ++r) {
                    float d = nxr[mt * 4 + r] + nec - 2.0f * acc[mt][nt][r];
                    if (d < minval[mt * 4 + r]) { minval[mt * 4 + r] = d; minidx[mt * 4 + r] = col; }
                }
        }
    }

    // reduce over the 16 col-lanes (lane bits 0-3), tie -> smaller index
    #pragma unroll
    for (int i = 0; i < 16; ++i) {
        float v = minval[i]; int ix = minidx[i];
        #pragma unroll
        for (int m = 1; m < 16; m <<= 1) {
            float ov = __shfl_xor(v, m, 64);
            int   oi = __shfl_xor(ix, m, 64);
            if (ov < v || (ov == v && oi < ix)) { v = ov; ix = oi; }
        }
        minval[i] = v; minidx[i] = ix;
    }
    __syncthreads();
    if (t16 == 0) {
        #pragma unroll
        for (int mt = 0; mt < 4; ++mt)
            #pragma unroll
            for (int r = 0; r < 4; ++r) {
                int rl = wy * 64 + mt * 16 + quad * 4 + r;
                sval2[wx][rl] = minval[mt * 4 + r];
                sidx2[wx][rl] = minidx[mt * 4 + r];
            }
    }
    __syncthreads();
    if (tid < 128) {
        float v0 = sval2[0][tid]; int i0 = sidx2[0][tid];
        float v1 = sval2[1][tid]; int i1 = sidx2[1][tid];
        if (v1 < v0 || (v1 == v0 && i1 < i0)) { v0 = v1; i0 = i1; }
        val_part[ks * ND_ROWS + rowBase + tid] = v0;
        idx_part[ks * ND_ROWS + rowBase + tid] = i0;
    }
}

__global__ __launch_bounds__(256) void finalize_kernel(
    const float* __restrict__ x, const float* __restrict__ emb,
    const float* __restrict__ val_part, const int* __restrict__ idx_part,
    float* __restrict__ out_q, float* __restrict__ out_idx,
    int* __restrict__ counts, float* __restrict__ sse) {
    int row  = (blockIdx.x << 2) + (threadIdx.x >> 6);
    int lane = threadIdx.x & 63;

    float bv = val_part[row];
    int   bi = idx_part[row];
    #pragma unroll
    for (int p = 1; p < NSPLIT; ++p) {
        float v  = val_part[p * ND_ROWS + row];
        int   i2 = idx_part[p * ND_ROWS + row];
        if (v < bv || (v == bv && i2 < bi)) { bv = v; bi = i2; }
    }

    float4 xv = ((const float4*)(x   + (size_t)row * DDIM))[lane];
    float4 ev = ((const float4*)(emb + (size_t)bi  * DDIM))[lane];
    float4 q;
    q.x = xv.x + (ev.x - xv.x);
    q.y = xv.y + (ev.y - xv.y);
    q.z = xv.z + (ev.z - xv.z);
    q.w = xv.w + (ev.w - xv.w);
    ((float4*)(out_q + (size_t)row * DDIM))[lane] = q;

    float de = (ev.x - xv.x) * (ev.x - xv.x) + (ev.y - xv.y) * (ev.y - xv.y)
             + (ev.z - xv.z) * (ev.z - xv.z) + (ev.w - xv.w) * (ev.w - xv.w);
    float dq = (q.x - ev.x) * (q.x - ev.x) + (q.y - ev.y) * (q.y - ev.y)
             + (q.z - ev.z) * (q.z - ev.z) + (q.w - ev.w) * (q.w - ev.w);
    #pragma unroll
    for (int m = 32; m; m >>= 1) {
        de += __shfl_xor(de, m, 64);
        dq += __shfl_xor(dq, m, 64);
    }
    if (lane == 0) {
        out_idx[row] = (float)bi;
        atomicAdd(&counts[bi], 1);
        atomicAdd(&sse[0], de);
        atomicAdd(&sse[1], dq);
    }
}

__global__ __launch_bounds__(256) void scalars_kernel(
    const int* __restrict__ counts, const float* __restrict__ sse,
    float* __restrict__ out_loss, float* __restrict__ out_perp) {
    __shared__ float red[256];
    float local = 0.0f;
    for (int k = threadIdx.x; k < KCODES; k += 256) {
        float p = (float)counts[k] * (1.0f / (float)ND_ROWS);
        local += p * logf(p + 1e-10f);
    }
    red[threadIdx.x] = local;
    __syncthreads();
    for (int s = 128; s; s >>= 1) {
        if (threadIdx.x < s) red[threadIdx.x] += red[threadIdx.x + s];
        __syncthreads();
    }
    if (threadIdx.x == 0) {
        *out_perp = expf(-red[0]);
        float invn = 1.0f / (float)(ND_ROWS * DDIM);
        *out_loss = sse[1] * invn + 0.25f * (sse[0] * invn);
    }
}

extern "C" void kernel_launch(void* const* d_in, const int* in_sizes, int n_in,
                              void* d_out, int out_size, void* d_ws, size_t ws_size,
                              hipStream_t stream) {
    const float* x   = (const float*)d_in[0];
    const float* emb = (const float*)d_in[1];

    float* ws       = (float*)d_ws;
    float* ne       = ws;
    float* nx       = ws + 8192;
    float* val_part = ws + 24576;
    int*   idx_part = (int*)(ws + 90112);
    int*   counts   = (int*)(ws + 155648);
    float* sse      = ws + 163840;
    _Float16* Ap    = (_Float16*)(ws + 163848);        // 16B-aligned
    _Float16* Bp    = Ap + (size_t)ND_ROWS * 512;

    float* out_q    = (float*)d_out;
    float* out_idx  = out_q + (size_t)ND_ROWS * DDIM;
    float* out_loss = out_idx + ND_ROWS;
    float* out_perp = out_loss + 1;

    hipMemsetAsync(counts, 0, KCODES * sizeof(int) + 2 * sizeof(float), stream);

    norms_kernel<<<(KCODES + ND_ROWS) / 4, 256, 0, stream>>>(x, emb, ne, nx);
    prep_kernel<<<(KCODES + ND_ROWS) * 64 / 256, 256, 0, stream>>>(x, emb, Ap, Bp);
    argmin_mfma<<<(ND_ROWS / 128) * NSPLIT, 256, 0, stream>>>(Ap, Bp, nx, ne,
                                                              val_part, idx_part);
    finalize_kernel<<<ND_ROWS / 4, 256, 0, stream>>>(x, emb, val_part, idx_part,
                                                     out_q, out_idx, counts, sse);
    scalars_kernel<<<1, 256, 0, stream>>>(counts, sse, out_loss, out_perp);
}

// Round 4
// 440.818 us; speedup vs baseline: 3.1642x; 2.0666x over previous
//
#include <hip/hip_runtime.h>
#include <math.h>
#include <stdint.h>

#define ND_ROWS 16384
#define DDIM    256
#define KCODES  8192
#define NSPLIT  8
#define KSEG    (KCODES / NSPLIT)   // 1024

typedef _Float16 f16x4 __attribute__((ext_vector_type(4)));
typedef _Float16 f16x8 __attribute__((ext_vector_type(8)));
typedef float    f32x4 __attribute__((ext_vector_type(4)));

// ---------------------------------------------------------------------------
// ws layout (float offsets):
//   ne        [0,      8192)
//   nx        [8192,   24576)
//   val_part  [24576,  155648)   8 x 16384 floats
//   idx_part  [155648, 286720)   8 x 16384 ints
//   counts    [286720, 294912)   8192 ints   (memset 0 each call)
//   parts     [294912, 303104)   de[4096] | dq[4096] per finalize block
//   Ap        [303104, ...)      16384x512 f16  ([x_hi | x_lo])
//   Bp        Ap + 16384*512     8192x512  f16  ([e_hi | e_lo])
// total ~26.4 MB
// ---------------------------------------------------------------------------

__device__ __attribute__((always_inline)) inline void load_lds16(const void* g, void* l) {
    __builtin_amdgcn_global_load_lds((const __attribute__((address_space(1))) void*)g,
                                     (__attribute__((address_space(3))) void*)l, 16, 0, 0);
}

// one wave per vector: fp16 hi/lo split + squared-norm (norms fused in)
__global__ __launch_bounds__(256) void prep_kernel(const float* __restrict__ x,
                                                   const float* __restrict__ emb,
                                                   _Float16* __restrict__ Ap,
                                                   _Float16* __restrict__ Bp,
                                                   float* __restrict__ nx,
                                                   float* __restrict__ ne) {
    int wave = (blockIdx.x << 2) + (threadIdx.x >> 6);   // [0, 24576)
    int lane = threadIdx.x & 63;
    const float* src;
    _Float16* dst;
    float* dstn;
    if (wave < ND_ROWS) { src = x + (size_t)wave * DDIM; dst = Ap + (size_t)wave * 512; dstn = nx + wave; }
    else { int r = wave - ND_ROWS; src = emb + (size_t)r * DDIM; dst = Bp + (size_t)r * 512; dstn = ne + r; }
    float4 v = ((const float4*)src)[lane];
    f16x4 hi, lo;
    hi[0] = (_Float16)v.x; lo[0] = (_Float16)(v.x - (float)hi[0]);
    hi[1] = (_Float16)v.y; lo[1] = (_Float16)(v.y - (float)hi[1]);
    hi[2] = (_Float16)v.z; lo[2] = (_Float16)(v.z - (float)hi[2]);
    hi[3] = (_Float16)v.w; lo[3] = (_Float16)(v.w - (float)hi[3]);
    *(f16x4*)(dst + lane * 4)       = hi;
    *(f16x4*)(dst + 256 + lane * 4) = lo;
    float s = v.x*v.x + v.y*v.y + v.z*v.z + v.w*v.w;
    #pragma unroll
    for (int m = 32; m; m >>= 1) s += __shfl_xor(s, m, 64);
    if (lane == 0) *dstn = s;
}

// MFMA argmin GEMM: logical K'=768 = [x1.e1 | x1.e2 | x2.e1].
// Block = 128 rows x 1024 codes (8-way col split, ks=blockIdx&7 -> XCD affinity),
// 4 waves of 64x64. LDS chunk slots XOR-swizzled: slot c holds chunk c^((row>>1)&3)
// so ds_read_b128 fragment reads are <=2-way bank-aliased (free, m136) while
// global_load_lds staging stays wave-uniform-base + lane*16.
__global__ __launch_bounds__(256, 4) void argmin_mfma(
    const _Float16* __restrict__ Ap, const _Float16* __restrict__ Bp,
    const float* __restrict__ nx, const float* __restrict__ ne,
    float* __restrict__ val_part, int* __restrict__ idx_part) {
    __shared__ __align__(16) _Float16 As[128 * 32];   // [row][64B], 8KB
    __shared__ __align__(16) _Float16 Bs[128 * 32];
    __shared__ float sval2[2][128];
    __shared__ int   sidx2[2][128];

    const int tid  = threadIdx.x;
    const int lane = tid & 63;
    const int w    = tid >> 6;
    const int wx   = w & 1;
    const int wy   = w >> 1;
    const int quad = lane >> 4;
    const int t16  = lane & 15;

    const int ks       = blockIdx.x & 7;    // XCD-affine code split
    const int rt       = blockIdx.x >> 3;   // 128 row tiles
    const int rowBase  = rt * 128;
    const int codeBase = ks * KSEG;

    // staging: wave w covers rows [w*32, w*32+32), lane -> (row=w*32+j*16+lane/4,
    // stored slot = lane&3). Fetch the XOR-permuted global chunk for that slot.
    const int srow   = (w << 5) + (lane >> 2);
    const int schunk = (lane & 3) ^ ((lane >> 3) & 3);   // chunk held by slot lane&3

    float nxr[16];
    #pragma unroll
    for (int mt = 0; mt < 4; ++mt)
        #pragma unroll
        for (int r = 0; r < 4; ++r)
            nxr[mt * 4 + r] = nx[rowBase + wy * 64 + mt * 16 + quad * 4 + r];

    float minval[16];
    int   minidx[16];
    #pragma unroll
    for (int i = 0; i < 16; ++i) { minval[i] = 3.402823466e+38f; minidx[i] = 0; }

    for (int jt = 0; jt < KSEG / 128; ++jt) {
        const int colBase = codeBase + jt * 128;
        f32x4 acc[4][4];
        #pragma unroll
        for (int mt = 0; mt < 4; ++mt)
            #pragma unroll
            for (int nt = 0; nt < 4; ++nt) {
                f32x4 z = {0.0f, 0.0f, 0.0f, 0.0f};
                acc[mt][nt] = z;
            }

        for (int kc = 0; kc < 768; kc += 32) {
            const int a_k = (kc < 256) ? kc : kc - 256;   // [x1 | x1 | x2]
            const int b_k = (kc < 512) ? kc : kc - 512;   // [e1 | e2 | e1]
            __syncthreads();
            #pragma unroll
            for (int j = 0; j < 2; ++j) {
                const char* gA = (const char*)(Ap + (size_t)(rowBase + srow + j * 16) * 512 + a_k)
                               + (schunk << 4);
                load_lds16(gA, (char*)As + (w << 11) + (j << 10));
                const char* gB = (const char*)(Bp + (size_t)(colBase + srow + j * 16) * 512 + b_k)
                               + (schunk << 4);
                load_lds16(gB, (char*)Bs + (w << 11) + (j << 10));
            }
            __syncthreads();

            f16x8 af[4], bf[4];
            #pragma unroll
            for (int mt = 0; mt < 4; ++mt) {
                int row = wy * 64 + mt * 16 + t16;
                int slot = quad ^ ((t16 >> 1) & 3);
                af[mt] = *(const f16x8*)((const char*)As + row * 64 + (slot << 4));
            }
            #pragma unroll
            for (int nt = 0; nt < 4; ++nt) {
                int row = wx * 64 + nt * 16 + t16;
                int slot = quad ^ ((t16 >> 1) & 3);
                bf[nt] = *(const f16x8*)((const char*)Bs + row * 64 + (slot << 4));
            }
            #pragma unroll
            for (int mt = 0; mt < 4; ++mt)
                #pragma unroll
                for (int nt = 0; nt < 4; ++nt)
                    acc[mt][nt] = __builtin_amdgcn_mfma_f32_16x16x32_f16(af[mt], bf[nt], acc[mt][nt], 0, 0, 0);
        }

        #pragma unroll
        for (int nt = 0; nt < 4; ++nt) {
            int col = colBase + wx * 64 + nt * 16 + t16;
            float nec = ne[col];
            #pragma unroll
            for (int mt = 0; mt < 4; ++mt)
                #pragma unroll
                for (int r = 0; r < 4; ++r) {
                    float d = nxr[mt * 4 + r] + nec - 2.0f * acc[mt][nt][r];
                    if (d < minval[mt * 4 + r]) { minval[mt * 4 + r] = d; minidx[mt * 4 + r] = col; }
                }
        }
    }

    // reduce over the 16 col-lanes (lane bits 0-3), tie -> smaller index
    #pragma unroll
    for (int i = 0; i < 16; ++i) {
        float v = minval[i]; int ix = minidx[i];
        #pragma unroll
        for (int m = 1; m < 16; m <<= 1) {
            float ov = __shfl_xor(v, m, 64);
            int   oi = __shfl_xor(ix, m, 64);
            if (ov < v || (ov == v && oi < ix)) { v = ov; ix = oi; }
        }
        minval[i] = v; minidx[i] = ix;
    }
    __syncthreads();
    if (t16 == 0) {
        #pragma unroll
        for (int mt = 0; mt < 4; ++mt)
            #pragma unroll
            for (int r = 0; r < 4; ++r) {
                int rl = wy * 64 + mt * 16 + quad * 4 + r;
                sval2[wx][rl] = minval[mt * 4 + r];
                sidx2[wx][rl] = minidx[mt * 4 + r];
            }
    }
    __syncthreads();
    if (tid < 128) {
        float v0 = sval2[0][tid]; int i0 = sidx2[0][tid];
        float v1 = sval2[1][tid]; int i1 = sidx2[1][tid];
        if (v1 < v0 || (v1 == v0 && i1 < i0)) { v0 = v1; i0 = i1; }
        val_part[ks * ND_ROWS + rowBase + tid] = v0;
        idx_part[ks * ND_ROWS + rowBase + tid] = i0;
    }
}

// merge splits, gather codebook row, write quantized_sg + float index,
// histogram atomic + per-block SSE partials (no same-address float atomics).
__global__ __launch_bounds__(256) void finalize_kernel(
    const float* __restrict__ x, const float* __restrict__ emb,
    const float* __restrict__ val_part, const int* __restrict__ idx_part,
    float* __restrict__ out_q, float* __restrict__ out_idx,
    int* __restrict__ counts, float* __restrict__ parts) {
    __shared__ float rde[4], rdq[4];
    int wv   = threadIdx.x >> 6;
    int row  = (blockIdx.x << 2) + wv;
    int lane = threadIdx.x & 63;

    float bv = val_part[row];
    int   bi = idx_part[row];
    #pragma unroll
    for (int p = 1; p < NSPLIT; ++p) {
        float v  = val_part[p * ND_ROWS + row];
        int   i2 = idx_part[p * ND_ROWS + row];
        if (v < bv || (v == bv && i2 < bi)) { bv = v; bi = i2; }
    }

    float4 xv = ((const float4*)(x   + (size_t)row * DDIM))[lane];
    float4 ev = ((const float4*)(emb + (size_t)bi  * DDIM))[lane];
    float4 q;
    q.x = xv.x + (ev.x - xv.x);
    q.y = xv.y + (ev.y - xv.y);
    q.z = xv.z + (ev.z - xv.z);
    q.w = xv.w + (ev.w - xv.w);
    ((float4*)(out_q + (size_t)row * DDIM))[lane] = q;

    float de = (ev.x - xv.x) * (ev.x - xv.x) + (ev.y - xv.y) * (ev.y - xv.y)
             + (ev.z - xv.z) * (ev.z - xv.z) + (ev.w - xv.w) * (ev.w - xv.w);
    float dq = (q.x - ev.x) * (q.x - ev.x) + (q.y - ev.y) * (q.y - ev.y)
             + (q.z - ev.z) * (q.z - ev.z) + (q.w - ev.w) * (q.w - ev.w);
    #pragma unroll
    for (int m = 32; m; m >>= 1) {
        de += __shfl_xor(de, m, 64);
        dq += __shfl_xor(dq, m, 64);
    }
    if (lane == 0) {
        out_idx[row] = (float)bi;
        atomicAdd(&counts[bi], 1);
        rde[wv] = de; rdq[wv] = dq;
    }
    __syncthreads();
    if (threadIdx.x == 0) {
        parts[blockIdx.x]        = rde[0] + rde[1] + rde[2] + rde[3];
        parts[4096 + blockIdx.x] = rdq[0] + rdq[1] + rdq[2] + rdq[3];
    }
}

__global__ __launch_bounds__(256) void scalars_kernel(
    const int* __restrict__ counts, const float* __restrict__ parts,
    float* __restrict__ out_loss, float* __restrict__ out_perp) {
    __shared__ float red[256], rde[256], rdq[256];
    float local = 0.0f, de = 0.0f, dq = 0.0f;
    for (int k = threadIdx.x; k < KCODES; k += 256) {
        float p = (float)counts[k] * (1.0f / (float)ND_ROWS);
        local += p * logf(p + 1e-10f);
    }
    for (int k = threadIdx.x; k < 4096; k += 256) {
        de += parts[k];
        dq += parts[4096 + k];
    }
    red[threadIdx.x] = local; rde[threadIdx.x] = de; rdq[threadIdx.x] = dq;
    __syncthreads();
    for (int s = 128; s; s >>= 1) {
        if (threadIdx.x < s) {
            red[threadIdx.x] += red[threadIdx.x + s];
            rde[threadIdx.x] += rde[threadIdx.x + s];
            rdq[threadIdx.x] += rdq[threadIdx.x + s];
        }
        __syncthreads();
    }
    if (threadIdx.x == 0) {
        *out_perp = expf(-red[0]);
        float invn = 1.0f / (float)(ND_ROWS * DDIM);
        *out_loss = rdq[0] * invn + 0.25f * (rde[0] * invn);
    }
}

extern "C" void kernel_launch(void* const* d_in, const int* in_sizes, int n_in,
                              void* d_out, int out_size, void* d_ws, size_t ws_size,
                              hipStream_t stream) {
    const float* x   = (const float*)d_in[0];
    const float* emb = (const float*)d_in[1];

    float* ws       = (float*)d_ws;
    float* ne       = ws;
    float* nx       = ws + 8192;
    float* val_part = ws + 24576;
    int*   idx_part = (int*)(ws + 155648);
    int*   counts   = (int*)(ws + 286720);
    float* parts    = ws + 294912;
    _Float16* Ap    = (_Float16*)(ws + 303104);        // 16B-aligned
    _Float16* Bp    = Ap + (size_t)ND_ROWS * 512;

    float* out_q    = (float*)d_out;
    float* out_idx  = out_q + (size_t)ND_ROWS * DDIM;
    float* out_loss = out_idx + ND_ROWS;
    float* out_perp = out_loss + 1;

    hipMemsetAsync(counts, 0, KCODES * sizeof(int), stream);

    prep_kernel<<<(KCODES + ND_ROWS) / 4, 256, 0, stream>>>(x, emb, Ap, Bp, nx, ne);
    argmin_mfma<<<(ND_ROWS / 128) * NSPLIT, 256, 0, stream>>>(Ap, Bp, nx, ne,
                                                              val_part, idx_part);
    finalize_kernel<<<ND_ROWS / 4, 256, 0, stream>>>(x, emb, val_part, idx_part,
                                                     out_q, out_idx, counts, parts);
    scalars_kernel<<<1, 256, 0, stream>>>(counts, parts, out_loss, out_perp);
}